// Round 10
// baseline (33.881 us; speedup 1.0000x reference)
//
#include <hip/hip_runtime.h>

typedef float v2 __attribute__((ext_vector_type(2)));

constexpr int NN = 1024;
constexpr int G  = 65;         // grid points; spacing 1/64 over [0,1]
constexpr float GS = 64.0f;    // cells per unit

__device__ __forceinline__ v2 splat2(float a) { v2 r; r.x = a; r.y = a; return r; }

// ---- kernel A: tabulate the flowfield on a GxG grid (4225 exact MLP evals) ----
__global__ __launch_bounds__(256) void table_kernel(
    const float* __restrict__ W1, const float* __restrict__ b1,
    const float* __restrict__ W2, const float* __restrict__ b2,
    const float* __restrict__ W3, const float* __restrict__ b3,
    v2* __restrict__ table)
{
    const int t = blockIdx.x * 256 + threadIdx.x;
    if (t >= G * G) return;
    const float x = (float)(t % G) * (1.0f / GS);
    const float y = (float)(t / G) * (1.0f / GS);

    float h1[10], h2[10];
#pragma unroll
    for (int k = 0; k < 10; ++k)
        h1[k] = tanhf(fmaf(x, W1[k], fmaf(y, W1[10 + k], b1[k])));
#pragma unroll
    for (int k = 0; k < 10; ++k) {
        float acc = b2[k];
#pragma unroll
        for (int l = 0; l < 10; ++l) acc = fmaf(h1[l], W2[10 * l + k], acc);
        h2[k] = tanhf(acc);
    }
    float f0 = b3[0], f1 = b3[1];
#pragma unroll
    for (int k = 0; k < 10; ++k) {
        f0 = fmaf(h2[k], W3[2 * k], f0);
        f1 = fmaf(h2[k], W3[2 * k + 1], f1);
    }
    v2 r; r.x = f0; r.y = f1;
    table[t] = r;
}

// ---- kernel B: per-pair cost; table staged in LDS (33.8 KB -> 4 blocks/CU) ----
__global__ __launch_bounds__(256) void flow_kernel(
    const float* __restrict__ pts,
    const v2* __restrict__ table,
    float* __restrict__ out)
{
    __shared__ v2 tab[G * G];
    for (int t = threadIdx.x; t < G * G; t += 256)
        tab[t] = table[t];
    __syncthreads();

    const int tid = blockIdx.x * 256 + threadIdx.x;
    const int i = tid >> 10;          // source point (uniform per block)
    const int j = tid & (NN - 1);     // target point (coalesced)

    const float x1x = pts[2 * i], x1y = pts[2 * i + 1];
    const float x2x = pts[2 * j], x2y = pts[2 * j + 1];
    const float dx = x2x - x1x, dy = x2y - x1y;

    // Exact non-contracted f32 sequence for the floor() step-count boundary.
    const float nrm2 = __fadd_rn(__fmul_rn(dx, dx), __fmul_rn(dy, dy));
    const float euc  = __fsqrt_rn(nrm2);
    const float se   = (euc > 0.0f) ? euc : 1.0f;
    const float ux   = __fdiv_rn(dx, se), uy = __fdiv_rn(dy, se);
    const int   nvi  = (int)floorf(__fdiv_rn(euc, 0.1f));
    const int   smax = (nvi < 15) ? nvi : 15;

    float cost = 0.0f;
#pragma unroll 1
    for (int s = 0; s <= smax; ++s) {
        const float ts = (float)s * 0.1f;
        const float px = fmaf(ts, ux, x1x);   // on-segment => in [0,1]^2 (clamped below)
        const float py = fmaf(ts, uy, x1y);

        float u = fminf(fmaxf(px * GS, 0.0f), GS);
        float v = fminf(fmaxf(py * GS, 0.0f), GS);
        int ix = (int)u; ix = (ix < G - 2) ? ix : (G - 2);
        int iy = (int)v; iy = (iy < G - 2) ? iy : (G - 2);
        const float tx = u - (float)ix;
        const float ty = v - (float)iy;

        const int idx = iy * G + ix;
        const v2 f00 = tab[idx],     f10 = tab[idx + 1];
        const v2 f01 = tab[idx + G], f11 = tab[idx + G + 1];
        const v2 fx0 = f00 + splat2(tx) * (f10 - f00);
        const v2 fx1 = f01 + splat2(tx) * (f11 - f01);
        const v2 f   = fx0 + splat2(ty) * (fx1 - fx0);

        const float dot = fmaf(f.x, dx, f.y * dy);
        // per_step = 0.1/(5e/(4+e)) = 0.02 + 0.08*exp(-dot)
        cost += fmaf(0.08f, exp2f(-dot * 1.44269504088896340736f), 0.02f);
    }

    out[tid] = (euc > 0.0f) ? cost : 0.0f;
}

extern "C" void kernel_launch(void* const* d_in, const int* in_sizes, int n_in,
                              void* d_out, int out_size, void* d_ws, size_t ws_size,
                              hipStream_t stream) {
    const float* pts = (const float*)d_in[0];
    const float* W1  = (const float*)d_in[1];
    const float* b1  = (const float*)d_in[2];
    const float* W2  = (const float*)d_in[3];
    const float* b2  = (const float*)d_in[4];
    const float* W3  = (const float*)d_in[5];
    const float* b3  = (const float*)d_in[6];
    float* out = (float*)d_out;
    v2* table = (v2*)d_ws;   // G*G*8 = 33800 bytes of scratch

    table_kernel<<<(G * G + 255) / 256, 256, 0, stream>>>(W1, b1, W2, b2, W3, b3, table);
    flow_kernel<<<(NN * NN) / 256, 256, 0, stream>>>(pts, table, out);
}

// Round 11
// 33.385 us; speedup vs baseline: 1.0148x; 1.0148x over previous
//
#include <hip/hip_runtime.h>

typedef float v2 __attribute__((ext_vector_type(2)));

constexpr int NN = 1024;
constexpr int G  = 129;        // table grid points; spacing 1/128
constexpr int GC = 128;        // cells
constexpr float GS = 128.0f;

__device__ __forceinline__ v2 splat2(float a) { v2 r; r.x = a; r.y = a; return r; }

// ---- kernel A: tabulate flowfield on GxG grid (exact tanhf MLP) ----
__global__ __launch_bounds__(256) void table_kernel(
    const float* __restrict__ W1, const float* __restrict__ b1,
    const float* __restrict__ W2, const float* __restrict__ b2,
    const float* __restrict__ W3, const float* __restrict__ b3,
    v2* __restrict__ table)
{
    const int t = blockIdx.x * 256 + threadIdx.x;
    if (t >= G * G) return;
    const float x = (float)(t % G) * (1.0f / GS);
    const float y = (float)(t / G) * (1.0f / GS);

    float h1[10], h2[10];
#pragma unroll
    for (int k = 0; k < 10; ++k)
        h1[k] = tanhf(fmaf(x, W1[k], fmaf(y, W1[10 + k], b1[k])));
#pragma unroll
    for (int k = 0; k < 10; ++k) {
        float acc = b2[k];
#pragma unroll
        for (int l = 0; l < 10; ++l) acc = fmaf(h1[l], W2[10 * l + k], acc);
        h2[k] = tanhf(acc);
    }
    float f0 = b3[0], f1 = b3[1];
#pragma unroll
    for (int k = 0; k < 10; ++k) {
        f0 = fmaf(h2[k], W3[2 * k], f0);
        f1 = fmaf(h2[k], W3[2 * k + 1], f1);
    }
    v2 r; r.x = f0; r.y = f1;
    table[t] = r;
}

// ---- kernel B: repack point-table into cell-duplicated layout (32 B/cell) ----
__global__ __launch_bounds__(256) void repack_kernel(
    const v2* __restrict__ table, float4* __restrict__ cells)
{
    const int t = blockIdx.x * 256 + threadIdx.x;
    if (t >= GC * GC) return;
    const int ix = t & (GC - 1), iy = t >> 7;
    const v2 f00 = table[iy * G + ix],       f10 = table[iy * G + ix + 1];
    const v2 f01 = table[(iy + 1) * G + ix], f11 = table[(iy + 1) * G + ix + 1];
    cells[2 * t]     = make_float4(f00.x, f00.y, f10.x, f10.y);
    cells[2 * t + 1] = make_float4(f01.x, f01.y, f11.x, f11.y);
}

// ---- kernel C: Morton-bucket the 1024 points (256 buckets, counting sort) ----
__global__ __launch_bounds__(1024) void sort_kernel(
    const float* __restrict__ pts, int* __restrict__ order)
{
    __shared__ int cnt[256];
    __shared__ int pre[256];
    const int t = threadIdx.x;   // 0..1023
    if (t < 256) cnt[t] = 0;
    __syncthreads();

    const float x = pts[2 * t], y = pts[2 * t + 1];
    int cx = (int)(x * 16.0f); cx = (cx < 15) ? cx : 15; cx = (cx > 0) ? cx : 0;
    int cy = (int)(y * 16.0f); cy = (cy < 15) ? cy : 15; cy = (cy > 0) ? cy : 0;
    int code = 0;
#pragma unroll
    for (int b = 0; b < 4; ++b)
        code |= (((cx >> b) & 1) << (2 * b)) | (((cy >> b) & 1) << (2 * b + 1));
    const int rank = atomicAdd(&cnt[code], 1);
    __syncthreads();

    if (t < 256) pre[t] = cnt[t];
    __syncthreads();
    for (int off = 1; off < 256; off <<= 1) {
        int v = 0;
        if (t < 256) { v = pre[t]; if (t >= off) v += pre[t - off]; }
        __syncthreads();
        if (t < 256) pre[t] = v;
        __syncthreads();
    }
    // exclusive base for this code:
    order[pre[code] - cnt[code] + rank] = t;
}

// ---- kernel D: per-pair cost, Morton-coherent lanes + cell gathers ----
__global__ __launch_bounds__(256) void flow_kernel(
    const float* __restrict__ pts,
    const float4* __restrict__ cells,
    const int* __restrict__ order,
    float* __restrict__ out)
{
    const int tid = blockIdx.x * 256 + threadIdx.x;
    const int i  = tid >> 10;             // source point (uniform per block)
    const int jj = order[tid & (NN - 1)]; // spatially-clustered target

    const float x1x = pts[2 * i],  x1y = pts[2 * i + 1];
    const float x2x = pts[2 * jj], x2y = pts[2 * jj + 1];
    const float dx = x2x - x1x, dy = x2y - x1y;

    // Exact non-contracted f32 sequence for the floor() step-count boundary.
    const float nrm2 = __fadd_rn(__fmul_rn(dx, dx), __fmul_rn(dy, dy));
    const float euc  = __fsqrt_rn(nrm2);
    const float se   = (euc > 0.0f) ? euc : 1.0f;
    const float ux   = __fdiv_rn(dx, se), uy = __fdiv_rn(dy, se);
    const int   nvi  = (int)floorf(__fdiv_rn(euc, 0.1f));
    const int   smax = (nvi < 15) ? nvi : 15;

    float cost = 0.0f;
#pragma unroll 1
    for (int s = 0; s <= smax; ++s) {
        const float ts = (float)s * 0.1f;
        const float px = fmaf(ts, ux, x1x);
        const float py = fmaf(ts, uy, x1y);

        const float u = fminf(fmaxf(px * GS, 0.0f), GS);
        const float v = fminf(fmaxf(py * GS, 0.0f), GS);
        int ix = (int)u; ix = (ix < GC - 1) ? ix : (GC - 1);
        int iy = (int)v; iy = (iy < GC - 1) ? iy : (GC - 1);
        const float tx = u - (float)ix;   // may hit 1.0 at the top edge: still exact
        const float ty = v - (float)iy;

        const float4* cp = cells + ((iy << 8) + (ix << 1));
        const float4 A = cp[0];   // f00.x f00.y f10.x f10.y
        const float4 B = cp[1];   // f01.x f01.y f11.x f11.y
        const float fx0x = A.x + tx * (A.z - A.x);
        const float fx0y = A.y + tx * (A.w - A.y);
        const float fx1x = B.x + tx * (B.z - B.x);
        const float fx1y = B.y + tx * (B.w - B.y);
        const float fx = fx0x + ty * (fx1x - fx0x);
        const float fy = fx0y + ty * (fx1y - fx0y);

        const float dot = fmaf(fx, dx, fy * dy);
        // per_step = 0.1/(5e/(4+e)) = 0.02 + 0.08*exp(-dot)
        cost += fmaf(0.08f, exp2f(-dot * 1.44269504088896340736f), 0.02f);
    }

    out[(i << 10) | jj] = (euc > 0.0f) ? cost : 0.0f;
}

extern "C" void kernel_launch(void* const* d_in, const int* in_sizes, int n_in,
                              void* d_out, int out_size, void* d_ws, size_t ws_size,
                              hipStream_t stream) {
    const float* pts = (const float*)d_in[0];
    const float* W1  = (const float*)d_in[1];
    const float* b1  = (const float*)d_in[2];
    const float* W2  = (const float*)d_in[3];
    const float* b2  = (const float*)d_in[4];
    const float* W3  = (const float*)d_in[5];
    const float* b3  = (const float*)d_in[6];
    float* out = (float*)d_out;

    char* ws = (char*)d_ws;                      // d_ws is ~256 MiB; we use < 1 MiB
    v2*     table = (v2*)(ws);                   // 129^2 * 8  = 133128 B
    float4* cells = (float4*)(ws + (256 << 10)); // 128^2 * 32 = 524288 B
    int*    order = (int*)(ws + (800 << 10));    // 4096 B

    table_kernel<<<(G * G + 255) / 256, 256, 0, stream>>>(W1, b1, W2, b2, W3, b3, table);
    repack_kernel<<<(GC * GC + 255) / 256, 256, 0, stream>>>(table, cells);
    sort_kernel<<<1, 1024, 0, stream>>>(pts, order);
    flow_kernel<<<(NN * NN) / 256, 256, 0, stream>>>(pts, cells, order, out);
}

// Round 13
// 32.964 us; speedup vs baseline: 1.0278x; 1.0128x over previous
//
#include <hip/hip_runtime.h>

typedef float v2 __attribute__((ext_vector_type(2)));

constexpr int NN = 1024;
constexpr int GC = 128;        // cells per side; corner grid is 129x129, spacing 1/128
constexpr float GS = 128.0f;

__device__ __forceinline__ v2 splat2(float a) { v2 r; r.x = a; r.y = a; return r; }

__device__ __forceinline__ v2 mlp_eval(float x, float y,
    const float* __restrict__ W1, const float* __restrict__ b1,
    const float* __restrict__ W2, const float* __restrict__ b2,
    const float* __restrict__ W3, const float* __restrict__ b3)
{
    float h1[10], h2[10];
#pragma unroll
    for (int k = 0; k < 10; ++k)
        h1[k] = tanhf(fmaf(x, W1[k], fmaf(y, W1[10 + k], b1[k])));
#pragma unroll
    for (int k = 0; k < 10; ++k) {
        float acc = b2[k];
#pragma unroll
        for (int l = 0; l < 10; ++l) acc = fmaf(h1[l], W2[10 * l + k], acc);
        h2[k] = tanhf(acc);
    }
    float f0 = b3[0], f1 = b3[1];
#pragma unroll
    for (int k = 0; k < 10; ++k) {
        f0 = fmaf(h2[k], W3[2 * k], f0);
        f1 = fmaf(h2[k], W3[2 * k + 1], f1);
    }
    v2 r; r.x = f0; r.y = f1;
    return r;
}

// ---- kernel A: per-cell 4-corner MLP -> cell-duplicated table (32 B/cell) ----
// Corner positions ix*(1/128) are exact, so shared corners agree across cells.
__global__ __launch_bounds__(256) void cells_kernel(
    const float* __restrict__ W1, const float* __restrict__ b1,
    const float* __restrict__ W2, const float* __restrict__ b2,
    const float* __restrict__ W3, const float* __restrict__ b3,
    float4* __restrict__ cells)
{
    const int t = blockIdx.x * 256 + threadIdx.x;
    if (t >= GC * GC) return;
    const int ix = t & (GC - 1), iy = t >> 7;
    const float x0 = (float)ix * (1.0f / GS), x1 = (float)(ix + 1) * (1.0f / GS);
    const float y0 = (float)iy * (1.0f / GS), y1 = (float)(iy + 1) * (1.0f / GS);

    const v2 f00 = mlp_eval(x0, y0, W1, b1, W2, b2, W3, b3);
    const v2 f10 = mlp_eval(x1, y0, W1, b1, W2, b2, W3, b3);
    const v2 f01 = mlp_eval(x0, y1, W1, b1, W2, b2, W3, b3);
    const v2 f11 = mlp_eval(x1, y1, W1, b1, W2, b2, W3, b3);

    cells[2 * t]     = make_float4(f00.x, f00.y, f10.x, f10.y);
    cells[2 * t + 1] = make_float4(f01.x, f01.y, f11.x, f11.y);
}

// ---- kernel B: per-pair cost; grid-unit incremental positions, packed bilinear ----
__global__ __launch_bounds__(256) void flow_kernel(
    const float* __restrict__ pts,
    const float4* __restrict__ cells,
    float* __restrict__ out)
{
    const int tid = blockIdx.x * 256 + threadIdx.x;
    const int i = tid >> 10;          // source point (uniform per block)
    const int j = tid & (NN - 1);     // target point (coalesced)

    const float x1x = pts[2 * i], x1y = pts[2 * i + 1];
    const float x2x = pts[2 * j], x2y = pts[2 * j + 1];
    const float dx = x2x - x1x, dy = x2y - x1y;

    // Exact non-contracted f32 sequence for the floor() step-count boundary.
    const float nrm2 = __fadd_rn(__fmul_rn(dx, dx), __fmul_rn(dy, dy));
    const float euc  = __fsqrt_rn(nrm2);
    const float se   = (euc > 0.0f) ? euc : 1.0f;
    const float ux   = __fdiv_rn(dx, se), uy = __fdiv_rn(dy, se);
    const int   nvi  = (int)floorf(__fdiv_rn(euc, 0.1f));
    const int   smax = (nvi < 15) ? nvi : 15;

    // Grid-unit incremental position; exp argument pre-scaled by -log2(e).
    float pu = x1x * GS, pv = x1y * GS;
    const float du = 12.8f * ux, dv = 12.8f * uy;          // 0.1 * GS
    const float dxe = -1.44269504088896340736f * dx;
    const float dye = -1.44269504088896340736f * dy;

    float cost = 0.0f;
#pragma unroll 1
    for (int s = 0; s <= smax; ++s) {
        int ix = (int)pu; ix = (ix < GC - 1) ? ix : (GC - 1);
        int iy = (int)pv; iy = (iy < GC - 1) ? iy : (GC - 1);
        const float tx = pu - (float)ix;
        const float ty = pv - (float)iy;

        const float4* cp = cells + (((iy << 7) + ix) << 1);
        const float4 A = cp[0];   // f00.x f00.y f10.x f10.y
        const float4 B = cp[1];   // f01.x f01.y f11.x f11.y

        v2 f00; f00.x = A.x; f00.y = A.y;
        v2 f10; f10.x = A.z; f10.y = A.w;
        v2 f01; f01.x = B.x; f01.y = B.y;
        v2 f11; f11.x = B.z; f11.y = B.w;
        const v2 fx0 = f00 + splat2(tx) * (f10 - f00);     // v_pk_fma path
        const v2 fx1 = f01 + splat2(tx) * (f11 - f01);
        const v2 f   = fx0 + splat2(ty) * (fx1 - fx0);

        const float de = fmaf(f.x, dxe, f.y * dye);        // = -dot*log2e
        cost += fmaf(0.08f, exp2f(de), 0.02f);             // 0.02 + 0.08*exp(-dot)

        pu += du; pv += dv;
    }

    out[tid] = (euc > 0.0f) ? cost : 0.0f;
}

extern "C" void kernel_launch(void* const* d_in, const int* in_sizes, int n_in,
                              void* d_out, int out_size, void* d_ws, size_t ws_size,
                              hipStream_t stream) {
    const float* pts = (const float*)d_in[0];
    const float* W1  = (const float*)d_in[1];
    const float* b1  = (const float*)d_in[2];
    const float* W2  = (const float*)d_in[3];
    const float* b2  = (const float*)d_in[4];
    const float* W3  = (const float*)d_in[5];
    const float* b3  = (const float*)d_in[6];
    float* out = (float*)d_out;

    float4* cells = (float4*)d_ws;   // 128^2 * 32 = 524288 B of scratch

    cells_kernel<<<(GC * GC + 255) / 256, 256, 0, stream>>>(W1, b1, W2, b2, W3, b3, cells);
    flow_kernel<<<(NN * NN) / 256, 256, 0, stream>>>(pts, cells, out);
}

// Round 14
// 28.076 us; speedup vs baseline: 1.2068x; 1.1741x over previous
//
#include <hip/hip_runtime.h>

typedef float v2 __attribute__((ext_vector_type(2)));

constexpr int NN = 1024;
constexpr int GC = 128;        // cells per side; corner grid 129x129, spacing 1/128
constexpr float GS = 128.0f;

__device__ __forceinline__ v2 splat2(float a) { v2 r; r.x = a; r.y = a; return r; }

__device__ __forceinline__ v2 mlp_eval(float x, float y,
    const float* __restrict__ W1, const float* __restrict__ b1,
    const float* __restrict__ W2, const float* __restrict__ b2,
    const float* __restrict__ W3, const float* __restrict__ b3)
{
    float h1[10], h2[10];
#pragma unroll
    for (int k = 0; k < 10; ++k)
        h1[k] = tanhf(fmaf(x, W1[k], fmaf(y, W1[10 + k], b1[k])));
#pragma unroll
    for (int k = 0; k < 10; ++k) {
        float acc = b2[k];
#pragma unroll
        for (int l = 0; l < 10; ++l) acc = fmaf(h1[l], W2[10 * l + k], acc);
        h2[k] = tanhf(acc);
    }
    float f0 = b3[0], f1 = b3[1];
#pragma unroll
    for (int k = 0; k < 10; ++k) {
        f0 = fmaf(h2[k], W3[2 * k], f0);
        f1 = fmaf(h2[k], W3[2 * k + 1], f1);
    }
    v2 r; r.x = f0; r.y = f1;
    return r;
}

// ---- kernel A: one corner per thread (4 per cell), coalesced 8B writes ----
// cells layout per cell c: v2 slots [f00, f10, f01, f11]  (= float4 A, B)
__global__ __launch_bounds__(256) void cells_kernel(
    const float* __restrict__ W1, const float* __restrict__ b1,
    const float* __restrict__ W2, const float* __restrict__ b2,
    const float* __restrict__ W3, const float* __restrict__ b3,
    v2* __restrict__ cells)
{
    const int t = blockIdx.x * 256 + threadIdx.x;
    if (t >= 4 * GC * GC) return;
    const int c = t >> 2, k = t & 3;
    const int ix = (c & (GC - 1)) + (k & 1);
    const int iy = (c >> 7) + (k >> 1);
    cells[t] = mlp_eval((float)ix * (1.0f / GS), (float)iy * (1.0f / GS),
                        W1, b1, W2, b2, W3, b3);
}

// ---- kernel B: block = one source i; angle-sorted j for ring-coherent gathers ----
__global__ __launch_bounds__(1024, 8) void flow_kernel(
    const float* __restrict__ pts,
    const float4* __restrict__ cells,
    float* __restrict__ out)
{
    __shared__ v2 ptsL[1024];
    __shared__ int h[1024];
    __shared__ int h2[1024];
    __shared__ unsigned short ord[1024];

    const int t = threadIdx.x;
    const int i = blockIdx.x;

    ptsL[t] = ((const v2*)pts)[t];
    h[t] = 0;
    __syncthreads();

    const float x1x = ptsL[i].x, x1y = ptsL[i].y;

    // diamond pseudo-angle of (pts[t] - x1), 1024 buckets
    {
        const float ddx = ptsL[t].x - x1x, ddy = ptsL[t].y - x1y;
        const float ax = fabsf(ddx), ay = fabsf(ddy);
        const float sum = ax + ay;
        const float r = (sum > 0.0f) ? ay * __builtin_amdgcn_rcpf(sum) : 0.0f;
        float a;
        if (ddy >= 0.0f) a = (ddx >= 0.0f) ? r : 2.0f - r;
        else             a = (ddx >= 0.0f) ? 4.0f - r : 2.0f + r;
        int key = (int)(a * 256.0f);
        key = (key < 1023) ? key : 1023;
        key = (key > 0) ? key : 0;

        atomicAdd(&h[key], 1);
        __syncthreads();
        const int myCnt = h[t];

        // inclusive Hillis-Steele scan over 1024 buckets (double-buffered)
        int* src = h; int* dst = h2;
        for (int off = 1; off < 1024; off <<= 1) {
            int x = src[t];
            if (t >= off) x += src[t - off];
            dst[t] = x;
            __syncthreads();
            int* tmp = src; src = dst; dst = tmp;
        }
        // exclusive base for bucket t goes into dst (the spare array)
        dst[t] = src[t] - myCnt;
        __syncthreads();
        const int rank = atomicAdd(&dst[key], 1);
        ord[rank] = (unsigned short)t;
        __syncthreads();
    }

    const int jj = ord[t];
    const float x2x = ptsL[jj].x, x2y = ptsL[jj].y;
    const float dx = x2x - x1x, dy = x2y - x1y;

    // Exact non-contracted f32 sequence for the floor() step-count boundary.
    const float nrm2 = __fadd_rn(__fmul_rn(dx, dx), __fmul_rn(dy, dy));
    const float euc  = __fsqrt_rn(nrm2);
    const float se   = (euc > 0.0f) ? euc : 1.0f;
    const float ux   = __fdiv_rn(dx, se), uy = __fdiv_rn(dy, se);
    const int   nvi  = (int)floorf(__fdiv_rn(euc, 0.1f));
    const int   smax = (nvi < 15) ? nvi : 15;

    // Grid-unit incremental position; exp argument pre-scaled by -log2(e).
    float pu = x1x * GS, pv = x1y * GS;
    const float du = 12.8f * ux, dv = 12.8f * uy;          // 0.1 * GS
    const float dxe = -1.44269504088896340736f * dx;
    const float dye = -1.44269504088896340736f * dy;

    float cost = 0.0f;
#pragma unroll 1
    for (int s = 0; s <= smax; ++s) {
        int ix = (int)pu; ix = (ix < GC - 1) ? ix : (GC - 1);
        int iy = (int)pv; iy = (iy < GC - 1) ? iy : (GC - 1);
        const float tx = pu - (float)ix;
        const float ty = pv - (float)iy;

        const float4* cp = cells + (((iy << 7) + ix) << 1);
        const float4 A = cp[0];   // f00.x f00.y f10.x f10.y
        const float4 B = cp[1];   // f01.x f01.y f11.x f11.y

        v2 f00; f00.x = A.x; f00.y = A.y;
        v2 f10; f10.x = A.z; f10.y = A.w;
        v2 f01; f01.x = B.x; f01.y = B.y;
        v2 f11; f11.x = B.z; f11.y = B.w;
        const v2 fx0 = f00 + splat2(tx) * (f10 - f00);
        const v2 fx1 = f01 + splat2(tx) * (f11 - f01);
        const v2 f   = fx0 + splat2(ty) * (fx1 - fx0);

        const float de = fmaf(f.x, dxe, f.y * dye);        // = -dot*log2e
        cost += fmaf(0.08f, exp2f(de), 0.02f);             // 0.02 + 0.08*exp(-dot)

        pu += du; pv += dv;
    }

    out[(i << 10) | jj] = (euc > 0.0f) ? cost : 0.0f;
}

extern "C" void kernel_launch(void* const* d_in, const int* in_sizes, int n_in,
                              void* d_out, int out_size, void* d_ws, size_t ws_size,
                              hipStream_t stream) {
    const float* pts = (const float*)d_in[0];
    const float* W1  = (const float*)d_in[1];
    const float* b1  = (const float*)d_in[2];
    const float* W2  = (const float*)d_in[3];
    const float* b2  = (const float*)d_in[4];
    const float* W3  = (const float*)d_in[5];
    const float* b3  = (const float*)d_in[6];
    float* out = (float*)d_out;

    v2* cells = (v2*)d_ws;   // 4 * 128^2 * 8 = 524288 B of scratch

    cells_kernel<<<(4 * GC * GC) / 256, 256, 0, stream>>>(W1, b1, W2, b2, W3, b3, cells);
    flow_kernel<<<NN, 1024, 0, stream>>>(pts, (const float4*)cells, out);
}

// Round 15
// 23.468 us; speedup vs baseline: 1.4437x; 1.1964x over previous
//
#include <hip/hip_runtime.h>

typedef float v2 __attribute__((ext_vector_type(2)));

constexpr int NN = 1024;
constexpr int GC = 64;          // cells per side; corner grid 65x65, spacing 1/64
constexpr float GS = 64.0f;
constexpr int NC = GC * GC;     // 4096 cells

__device__ __forceinline__ v2 splat2(float a) { v2 r; r.x = a; r.y = a; return r; }

__device__ __forceinline__ float fast_tanh(float x) {
    // tanh via native exp2: error ~1e-6, negligible vs interpolation error
    float e = exp2f(x * 2.88539008177792681472f);
    return 1.0f - 2.0f * __builtin_amdgcn_rcpf(1.0f + e);
}

__device__ __forceinline__ v2 mlp_eval(float x, float y,
    const float* __restrict__ W1, const float* __restrict__ b1,
    const float* __restrict__ W2, const float* __restrict__ b2,
    const float* __restrict__ W3, const float* __restrict__ b3)
{
    float h1[10], h2[10];
#pragma unroll
    for (int k = 0; k < 10; ++k)
        h1[k] = fast_tanh(fmaf(x, W1[k], fmaf(y, W1[10 + k], b1[k])));
#pragma unroll
    for (int k = 0; k < 10; ++k) {
        float acc = b2[k];
#pragma unroll
        for (int l = 0; l < 10; ++l) acc = fmaf(h1[l], W2[10 * l + k], acc);
        h2[k] = fast_tanh(acc);
    }
    float f0 = b3[0], f1 = b3[1];
#pragma unroll
    for (int k = 0; k < 10; ++k) {
        f0 = fmaf(h2[k], W3[2 * k], f0);
        f1 = fmaf(h2[k], W3[2 * k + 1], f1);
    }
    v2 r; r.x = f0; r.y = f1;
    return r;
}

// ---- kernel A: per-cell plane model {f00, dfx, dfy}, SoA in d_ws ----
__global__ __launch_bounds__(256) void cells_kernel(
    const float* __restrict__ W1, const float* __restrict__ b1,
    const float* __restrict__ W2, const float* __restrict__ b2,
    const float* __restrict__ W3, const float* __restrict__ b3,
    v2* __restrict__ g)
{
    const int c = blockIdx.x * 256 + threadIdx.x;
    if (c >= NC) return;
    const int ix = c & (GC - 1), iy = c >> 6;
    const float x0 = (float)ix * (1.0f / GS), x1 = (float)(ix + 1) * (1.0f / GS);
    const float y0 = (float)iy * (1.0f / GS), y1 = (float)(iy + 1) * (1.0f / GS);

    const v2 f00 = mlp_eval(x0, y0, W1, b1, W2, b2, W3, b3);
    const v2 f10 = mlp_eval(x1, y0, W1, b1, W2, b2, W3, b3);
    const v2 f01 = mlp_eval(x0, y1, W1, b1, W2, b2, W3, b3);

    g[c]          = f00;
    g[NC + c]     = f10 - f00;   // dfx
    g[2 * NC + c] = f01 - f00;   // dfy
}

// ---- kernel B: persistent blocks; LDS-resident plane table; 4 sources/block ----
__global__ __launch_bounds__(1024) void flow_kernel(
    const float* __restrict__ pts,
    const v2* __restrict__ g,
    float* __restrict__ out)
{
    __shared__ v2 tab[3 * NC];   // 96 KB -> 1 block/CU, 16 waves

    const int t = threadIdx.x;
    {   // stage 96 KB, coalesced float4
        const float4* gs = (const float4*)g;
        float4* ls = (float4*)tab;
#pragma unroll
        for (int k = 0; k < 6; ++k)
            ls[t + 1024 * k] = gs[t + 1024 * k];
    }
    __syncthreads();

    const float x2x = pts[2 * t], x2y = pts[2 * t + 1];   // this thread's target

#pragma unroll 1
    for (int q = 0; q < 4; ++q) {
        const int i = (blockIdx.x << 2) + q;              // source (uniform)
        const float x1x = pts[2 * i], x1y = pts[2 * i + 1];
        const float dx = x2x - x1x, dy = x2y - x1y;

        // Exact non-contracted f32 sequence for the floor() step-count boundary.
        const float nrm2 = __fadd_rn(__fmul_rn(dx, dx), __fmul_rn(dy, dy));
        const float euc  = __fsqrt_rn(nrm2);
        const float se   = (euc > 0.0f) ? euc : 1.0f;
        const float ux   = __fdiv_rn(dx, se), uy = __fdiv_rn(dy, se);
        const int   nvi  = (int)floorf(__fdiv_rn(euc, 0.1f));
        const int   smax = (nvi < 15) ? nvi : 15;

        float pu = x1x * GS, pv = x1y * GS;
        const float du = 6.4f * ux, dv = 6.4f * uy;       // 0.1 * GS
        const float dxe = -1.44269504088896340736f * dx;
        const float dye = -1.44269504088896340736f * dy;

        float cost = 0.0f;
#pragma unroll 1
        for (int s = 0; s <= smax; ++s) {
            int ix = (int)pu; ix = (ix < GC - 1) ? ix : (GC - 1);
            int iy = (int)pv; iy = (iy < GC - 1) ? iy : (GC - 1);
            const float tx = pu - (float)ix;
            const float ty = pv - (float)iy;

            const int c = (iy << 6) + ix;
            const v2 a   = tab[c];
            const v2 gdx = tab[NC + c];
            const v2 gdy = tab[2 * NC + c];
            const v2 f = a + splat2(tx) * gdx + splat2(ty) * gdy;  // plane (pk_fma)

            const float de = fmaf(f.x, dxe, f.y * dye);   // = -dot*log2e
            cost += fmaf(0.08f, exp2f(de), 0.02f);        // 0.02 + 0.08*exp(-dot)

            pu += du; pv += dv;
        }

        out[(i << 10) | t] = (euc > 0.0f) ? cost : 0.0f;
    }
}

extern "C" void kernel_launch(void* const* d_in, const int* in_sizes, int n_in,
                              void* d_out, int out_size, void* d_ws, size_t ws_size,
                              hipStream_t stream) {
    const float* pts = (const float*)d_in[0];
    const float* W1  = (const float*)d_in[1];
    const float* b1  = (const float*)d_in[2];
    const float* W2  = (const float*)d_in[3];
    const float* b2  = (const float*)d_in[4];
    const float* W3  = (const float*)d_in[5];
    const float* b3  = (const float*)d_in[6];
    float* out = (float*)d_out;

    v2* g = (v2*)d_ws;   // 3 * 4096 * 8 = 98304 B of scratch

    cells_kernel<<<NC / 256, 256, 0, stream>>>(W1, b1, W2, b2, W3, b3, g);
    flow_kernel<<<NN / 4, 1024, 0, stream>>>(pts, g, out);
}

// Round 16
// 22.566 us; speedup vs baseline: 1.5014x; 1.0400x over previous
//
#include <hip/hip_runtime.h>

typedef float v2 __attribute__((ext_vector_type(2)));

constexpr int NN = 1024;
constexpr int GC = 64;          // cells per side; corner grid 65x65, spacing 1/64
constexpr float GS = 64.0f;
constexpr int NC = GC * GC;     // 4096 cells

__device__ __forceinline__ v2 splat2(float a) { v2 r; r.x = a; r.y = a; return r; }

__device__ __forceinline__ float fast_tanh(float x) {
    float e = exp2f(x * 2.88539008177792681472f);
    return 1.0f - 2.0f * __builtin_amdgcn_rcpf(1.0f + e);
}

__device__ __forceinline__ v2 mlp_eval(float x, float y,
    const float* __restrict__ W1, const float* __restrict__ b1,
    const float* __restrict__ W2, const float* __restrict__ b2,
    const float* __restrict__ W3, const float* __restrict__ b3)
{
    float h1[10], h2[10];
#pragma unroll
    for (int k = 0; k < 10; ++k)
        h1[k] = fast_tanh(fmaf(x, W1[k], fmaf(y, W1[10 + k], b1[k])));
#pragma unroll
    for (int k = 0; k < 10; ++k) {
        float acc = b2[k];
#pragma unroll
        for (int l = 0; l < 10; ++l) acc = fmaf(h1[l], W2[10 * l + k], acc);
        h2[k] = fast_tanh(acc);
    }
    float f0 = b3[0], f1 = b3[1];
#pragma unroll
    for (int k = 0; k < 10; ++k) {
        f0 = fmaf(h2[k], W3[2 * k], f0);
        f1 = fmaf(h2[k], W3[2 * k + 1], f1);
    }
    v2 r; r.x = f0; r.y = f1;
    return r;
}

// ---- kernel A: per-cell plane model {f00, dfx, dfy}, SoA in d_ws ----
__global__ __launch_bounds__(256) void cells_kernel(
    const float* __restrict__ W1, const float* __restrict__ b1,
    const float* __restrict__ W2, const float* __restrict__ b2,
    const float* __restrict__ W3, const float* __restrict__ b3,
    v2* __restrict__ g)
{
    const int c = blockIdx.x * 256 + threadIdx.x;
    if (c >= NC) return;
    const int ix = c & (GC - 1), iy = c >> 6;
    const float x0 = (float)ix * (1.0f / GS), x1 = (float)(ix + 1) * (1.0f / GS);
    const float y0 = (float)iy * (1.0f / GS), y1 = (float)(iy + 1) * (1.0f / GS);

    const v2 f00 = mlp_eval(x0, y0, W1, b1, W2, b2, W3, b3);
    const v2 f10 = mlp_eval(x1, y0, W1, b1, W2, b2, W3, b3);
    const v2 f01 = mlp_eval(x0, y1, W1, b1, W2, b2, W3, b3);

    g[c]          = f00;
    g[NC + c]     = f10 - f00;   // dfx
    g[2 * NC + c] = f01 - f00;   // dfy
}

// ---- kernel B: persistent blocks; LDS plane table; 4 sources/block;
//      global smax-sorted work list -> balanced, divergence-free waves ----
__global__ __launch_bounds__(1024) void flow_kernel(
    const float* __restrict__ pts,
    const v2* __restrict__ g,
    float* __restrict__ out)
{
    __shared__ v2 tab[3 * NC];              // 96 KB
    __shared__ v2 ptsL[NN];                 // 8 KB
    __shared__ unsigned short ordQ[4 * NN]; // 8 KB: sorted (q,j) items
    __shared__ int hist[16];
    __shared__ int base[16];

    const int t = threadIdx.x;

    {   // stage table + points, coalesced
        const float4* gs = (const float4*)g;
        float4* ls = (float4*)tab;
#pragma unroll
        for (int k = 0; k < 6; ++k)
            ls[t + 1024 * k] = gs[t + 1024 * k];
        ptsL[t] = ((const v2*)pts)[t];
    }
    if (t < 16) hist[t] = 0;
    __syncthreads();

    // ---- sort phase: key = smax(i(q), j=t), 16 buckets, all 4 sources ----
    int myKey[4];
#pragma unroll
    for (int q = 0; q < 4; ++q) {
        const int i = (blockIdx.x << 2) + q;
        const float ddx = ptsL[t].x - ptsL[i].x;
        const float ddy = ptsL[t].y - ptsL[i].y;
        const float n2 = __fadd_rn(__fmul_rn(ddx, ddx), __fmul_rn(ddy, ddy));
        const float e  = __fsqrt_rn(n2);
        const int  nv  = (int)floorf(__fdiv_rn(e, 0.1f));
        myKey[q] = (nv < 15) ? nv : 15;
        atomicAdd(&hist[myKey[q]], 1);
    }
    __syncthreads();
    if (t == 0) {
        int acc = 0;
#pragma unroll
        for (int k = 0; k < 16; ++k) { base[k] = acc; acc += hist[k]; }
    }
    __syncthreads();
#pragma unroll
    for (int q = 0; q < 4; ++q) {
        const int rank = atomicAdd(&base[myKey[q]], 1);
        ordQ[rank] = (unsigned short)((q << 10) | t);
    }
    __syncthreads();

    // ---- main phase: 4 rounds, no barriers; wave slices sit at even quantiles ----
#pragma unroll 1
    for (int r = 0; r < 4; ++r) {
        const int item = ordQ[(r << 10) + t];
        const int q = item >> 10, jj = item & (NN - 1);
        const int i = (blockIdx.x << 2) + q;

        const float x1x = ptsL[i].x,  x1y = ptsL[i].y;
        const float x2x = ptsL[jj].x, x2y = ptsL[jj].y;
        const float dx = x2x - x1x, dy = x2y - x1y;

        // Exact non-contracted f32 sequence for the floor() step-count boundary.
        const float nrm2 = __fadd_rn(__fmul_rn(dx, dx), __fmul_rn(dy, dy));
        const float euc  = __fsqrt_rn(nrm2);
        const float se   = (euc > 0.0f) ? euc : 1.0f;
        const float ux   = __fdiv_rn(dx, se), uy = __fdiv_rn(dy, se);
        const int   nvi  = (int)floorf(__fdiv_rn(euc, 0.1f));
        const int   smax = (nvi < 15) ? nvi : 15;

        float pu = x1x * GS, pv = x1y * GS;
        const float du = 6.4f * ux, dv = 6.4f * uy;       // 0.1 * GS
        const float dxe = -1.44269504088896340736f * dx;
        const float dye = -1.44269504088896340736f * dy;

        float cost = 0.0f;
#pragma unroll 1
        for (int s = 0; s <= smax; ++s) {
            int ix = (int)pu; ix = (ix < GC - 1) ? ix : (GC - 1);
            int iy = (int)pv; iy = (iy < GC - 1) ? iy : (GC - 1);
            const float tx = pu - (float)ix;
            const float ty = pv - (float)iy;

            const int c = (iy << 6) + ix;
            const v2 a   = tab[c];
            const v2 gdx = tab[NC + c];
            const v2 gdy = tab[2 * NC + c];
            const v2 f = a + splat2(tx) * gdx + splat2(ty) * gdy;  // plane (pk_fma)

            const float de = fmaf(f.x, dxe, f.y * dye);   // = -dot*log2e
            cost += fmaf(0.08f, exp2f(de), 0.02f);        // 0.02 + 0.08*exp(-dot)

            pu += du; pv += dv;
        }

        out[(i << 10) | jj] = (euc > 0.0f) ? cost : 0.0f;
    }
}

extern "C" void kernel_launch(void* const* d_in, const int* in_sizes, int n_in,
                              void* d_out, int out_size, void* d_ws, size_t ws_size,
                              hipStream_t stream) {
    const float* pts = (const float*)d_in[0];
    const float* W1  = (const float*)d_in[1];
    const float* b1  = (const float*)d_in[2];
    const float* W2  = (const float*)d_in[3];
    const float* b2  = (const float*)d_in[4];
    const float* W3  = (const float*)d_in[5];
    const float* b3  = (const float*)d_in[6];
    float* out = (float*)d_out;

    v2* g = (v2*)d_ws;   // 3 * 4096 * 8 = 98304 B of scratch

    cells_kernel<<<NC / 256, 256, 0, stream>>>(W1, b1, W2, b2, W3, b3, g);
    flow_kernel<<<NN / 4, 1024, 0, stream>>>(pts, g, out);
}

// Round 17
// 22.180 us; speedup vs baseline: 1.5276x; 1.0174x over previous
//
#include <hip/hip_runtime.h>
#include <hip/hip_fp16.h>

typedef float v2 __attribute__((ext_vector_type(2)));

constexpr int NN = 1024;
constexpr int GC = 64;          // cells per side; corner grid 65x65, spacing 1/64
constexpr float GS = 64.0f;
constexpr int NC = GC * GC;     // 4096 cells

__device__ __forceinline__ float fast_tanh(float x) {
    float e = exp2f(x * 2.88539008177792681472f);
    return 1.0f - 2.0f * __builtin_amdgcn_rcpf(1.0f + e);
}

__device__ __forceinline__ v2 mlp_eval(float x, float y,
    const float* __restrict__ W1, const float* __restrict__ b1,
    const float* __restrict__ W2, const float* __restrict__ b2,
    const float* __restrict__ W3, const float* __restrict__ b3)
{
    float h1[10], h2[10];
#pragma unroll
    for (int k = 0; k < 10; ++k)
        h1[k] = fast_tanh(fmaf(x, W1[k], fmaf(y, W1[10 + k], b1[k])));
#pragma unroll
    for (int k = 0; k < 10; ++k) {
        float acc = b2[k];
#pragma unroll
        for (int l = 0; l < 10; ++l) acc = fmaf(h1[l], W2[10 * l + k], acc);
        h2[k] = fast_tanh(acc);
    }
    float f0 = b3[0], f1 = b3[1];
#pragma unroll
    for (int k = 0; k < 10; ++k) {
        f0 = fmaf(h2[k], W3[2 * k], f0);
        f1 = fmaf(h2[k], W3[2 * k + 1], f1);
    }
    v2 r; r.x = f0; r.y = f1;
    return r;
}

__device__ __forceinline__ unsigned pack2h(float lo, float hi) {
    return (unsigned)__half_as_ushort(__float2half(lo))
         | ((unsigned)__half_as_ushort(__float2half(hi)) << 16);
}

__device__ __forceinline__ float2 unpack2h(unsigned u) {
    union { unsigned x; __half2 h; } c; c.x = u;
    return __half22float2(c.h);
}

// ---- kernel A: per-cell plane model packed as 6 x f16 in one 16B slot ----
__global__ __launch_bounds__(256) void cells_kernel(
    const float* __restrict__ W1, const float* __restrict__ b1,
    const float* __restrict__ W2, const float* __restrict__ b2,
    const float* __restrict__ W3, const float* __restrict__ b3,
    uint4* __restrict__ g)
{
    const int c = blockIdx.x * 256 + threadIdx.x;
    if (c >= NC) return;
    const int ix = c & (GC - 1), iy = c >> 6;
    const float x0 = (float)ix * (1.0f / GS), x1 = (float)(ix + 1) * (1.0f / GS);
    const float y0 = (float)iy * (1.0f / GS), y1 = (float)(iy + 1) * (1.0f / GS);

    const v2 f00 = mlp_eval(x0, y0, W1, b1, W2, b2, W3, b3);
    const v2 f10 = mlp_eval(x1, y0, W1, b1, W2, b2, W3, b3);
    const v2 f01 = mlp_eval(x0, y1, W1, b1, W2, b2, W3, b3);

    uint4 w;
    w.x = pack2h(f00.x, f00.y);
    w.y = pack2h(f10.x - f00.x, f10.y - f00.y);   // dfx
    w.z = pack2h(f01.x - f00.x, f01.y - f00.y);   // dfy
    w.w = 0;
    g[c] = w;
}

// ---- kernel B: LDS f16 plane table, one ds_read_b128 per step; 2 sources/block ----
__global__ __launch_bounds__(1024, 8) void flow_kernel(
    const float* __restrict__ pts,
    const uint4* __restrict__ g,
    float* __restrict__ out)
{
    __shared__ uint4 tabL[NC];   // 64 KB -> 2 blocks/CU, 8 waves/SIMD

    const int t = threadIdx.x;
#pragma unroll
    for (int k = 0; k < 4; ++k)
        tabL[t + 1024 * k] = g[t + 1024 * k];
    __syncthreads();

    const v2 pj = ((const v2*)pts)[t];    // this thread's target (coalesced)
    const float x2x = pj.x, x2y = pj.y;

#pragma unroll 1
    for (int q = 0; q < 2; ++q) {
        const int i = (blockIdx.x << 1) + q;              // source (uniform)
        const float x1x = pts[2 * i], x1y = pts[2 * i + 1];
        const float dx = x2x - x1x, dy = x2y - x1y;

        // Exact non-contracted f32 sequence for the floor() step-count boundary.
        const float nrm2 = __fadd_rn(__fmul_rn(dx, dx), __fmul_rn(dy, dy));
        const float euc  = __fsqrt_rn(nrm2);
        const float se   = (euc > 0.0f) ? euc : 1.0f;
        const float ux   = __fdiv_rn(dx, se), uy = __fdiv_rn(dy, se);
        const int   nvi  = (int)floorf(__fdiv_rn(euc, 0.1f));
        const int   smax = (nvi < 15) ? nvi : 15;

        float pu = x1x * GS, pv = x1y * GS;
        const float du = 6.4f * ux, dv = 6.4f * uy;       // 0.1 * GS
        const float dxe = -1.44269504088896340736f * dx;
        const float dye = -1.44269504088896340736f * dy;

        float cost = 0.0f;
#pragma unroll 1
        for (int s = 0; s <= smax; ++s) {
            int ix = (int)pu; ix = (ix < GC - 1) ? ix : (GC - 1);
            int iy = (int)pv; iy = (iy < GC - 1) ? iy : (GC - 1);
            const float tx = pu - (float)ix;
            const float ty = pv - (float)iy;

            const uint4 w = tabL[(iy << 6) + ix];         // single ds_read_b128
            const float2 a   = unpack2h(w.x);
            const float2 gdx = unpack2h(w.y);
            const float2 gdy = unpack2h(w.z);
            const float fx = fmaf(ty, gdy.x, fmaf(tx, gdx.x, a.x));
            const float fy = fmaf(ty, gdy.y, fmaf(tx, gdx.y, a.y));

            const float de = fmaf(fx, dxe, fy * dye);     // = -dot*log2e
            cost += fmaf(0.08f, exp2f(de), 0.02f);        // 0.02 + 0.08*exp(-dot)

            pu += du; pv += dv;
        }

        out[(i << 10) | t] = (euc > 0.0f) ? cost : 0.0f;
    }
}

extern "C" void kernel_launch(void* const* d_in, const int* in_sizes, int n_in,
                              void* d_out, int out_size, void* d_ws, size_t ws_size,
                              hipStream_t stream) {
    const float* pts = (const float*)d_in[0];
    const float* W1  = (const float*)d_in[1];
    const float* b1  = (const float*)d_in[2];
    const float* W2  = (const float*)d_in[3];
    const float* b2  = (const float*)d_in[4];
    const float* W3  = (const float*)d_in[5];
    const float* b3  = (const float*)d_in[6];
    float* out = (float*)d_out;

    uint4* g = (uint4*)d_ws;   // 4096 * 16 = 65536 B of scratch

    cells_kernel<<<NC / 256, 256, 0, stream>>>(W1, b1, W2, b2, W3, b3, g);
    flow_kernel<<<NN / 2, 1024, 0, stream>>>(pts, g, out);
}